// Round 7
// baseline (264.369 us; speedup 1.0000x reference)
//
#include <hip/hip_runtime.h>
#include <math.h>

#define NTOK   16384
#define DDIM   2048
#define EDIM   128
#define HDIM   128
#define TOKT   32
#define NRND   16            // rounds of 128 k each
#define KRND   128

typedef __attribute__((ext_vector_type(8)))  _Float16 half8;
typedef __attribute__((ext_vector_type(16))) float    f32x16;

#define MFMA32 __builtin_amdgcn_mfma_f32_32x32x16_f16

// b32-granule XOR swizzle for A[32][128] f32: conflict-free row+column.
__device__ __forceinline__ int swz(int t, int e) {
  return t * EDIM + ((e & 96) | ((e ^ t) & 31));
}

__device__ __forceinline__ void cvt8(const float4& a, const float4& b,
                                     half8& h, half8& l) {
#pragma unroll
  for (int m = 0; m < 4; ++m) {
    const float v = (&a.x)[m];
    const _Float16 hv = (_Float16)v;
    h[m] = hv; l[m] = (_Float16)((v - (float)hv) * 2048.0f);
  }
#pragma unroll
  for (int m = 0; m < 4; ++m) {
    const float v = (&b.x)[m];
    const _Float16 hv = (_Float16)v;
    h[m + 4] = hv; l[m + 4] = (_Float16)((v - (float)hv) * 2048.0f);
  }
}

// ---- W pre-convert: 32x32x16-fragment-ordered f16 hi/lo planes ----
// elem idx -> (nt, ks, lane, j); lane holds B[k=ks*16+(lane>>5)*8+j][n=nt*32+(lane&31)]
// = Wr[n][k], scaled by 32 (hi) and 32*2048 (lo) to dodge f16 denormals.
__global__ __launch_bounds__(256)
void conv_w(const float* __restrict__ Wr,
            _Float16* __restrict__ wh, _Float16* __restrict__ wl) {
  const int idx  = (int)blockIdx.x * 256 + (int)threadIdx.x;  // 0..32767
  const int lane = idx & 63;
  const int ks   = (idx >> 6) & 127;
  const int nt   = idx >> 13;                                 // 0..3
  const int n    = nt * 32 + (lane & 31);
  const int k0   = ks * 16 + (lane >> 5) * 8;
  half8 h, l;
#pragma unroll
  for (int j = 0; j < 8; ++j) {
    const float w = Wr[(size_t)n * DDIM + k0 + j] * 32.0f;
    const _Float16 hh = (_Float16)w;
    h[j] = hh;
    l[j] = (_Float16)((w - (float)hh) * 2048.0f);
  }
  *(half8*)(wh + (size_t)idx * 8) = h;
  *(half8*)(wl + (size_t)idx * 8) = l;
}

__global__ __launch_bounds__(1024, 8)
void fused_router(const float* __restrict__ x,
                  const _Float16* __restrict__ wsh,
                  const _Float16* __restrict__ wsl,
                  const float* __restrict__ Wd,
                  const float* __restrict__ gamma,
                  const float* __restrict__ beta,
                  const float* __restrict__ rnn,
                  const float* __restrict__ gum,
                  float* __restrict__ outb,
                  float* __restrict__ outa) {
  // 512 blocks = 2 blocks/CU (the first true co-residency test on the clean
  // structure). GEMM: x ONLY in LDS, double-buffered 2 x 16 KB, one barrier
  // per round. 16 waves = 1m x 4n x 4-way K-split (W dup/block = 1x).
  // Reduce: kw1/2/3 -> LDS scratch, kw0 sums + rnn -> A.
  // Regions: staging [0,32K); A=[0,16K), S1/S2/S3 at 16K/32K/48K; G4=[16K,32K).
  __shared__ char smraw[65536];
  char* const sm = smraw;
  float* const A  = (float*)smraw;
  float* const S1 = (float*)(smraw + 16384);
  float* const S2 = (float*)(smraw + 32768);
  float* const S3 = (float*)(smraw + 49152);
  float* const G4 = (float*)(smraw + 16384);

  const int tid  = (int)threadIdx.x;
  const int wv   = __builtin_amdgcn_readfirstlane(tid >> 6);  // 0..15
  const int lane = tid & 63;
  const int t0   = (int)blockIdx.x * TOKT;

  // wave -> one 32x32 C tile slice: nt = e quarter, kw = K quarter
  const int kw = wv >> 2;           // 0..3
  const int nt = wv & 3;            // 0..3

  // x staging: waves 0..7 (tid<512): thread -> (token, 8 consecutive k)
  const bool stg   = tid < 512;
  const int  s_tok = (tid & 3) + ((tid >> 6) << 2);   // 0..31
  const int  s_kq  = (tid >> 2) & 15;                 // 8-k octant within round
  const int  s_s   = s_kq >> 1;
  const int  s_ko  = s_kq & 1;
  const float* xg  = x + (size_t)(t0 + s_tok) * DDIM + s_kq * 8;
  const int  wbase = s_s * 2048;                      // + pl*1024
  const int  wslot = ((s_ko * 32 + s_tok) ^ s_s ^ (s_ko * 4)) * 16;

  // W direct-to-reg: elem offset = ((nt*128 + ks)*64 + lane)*8
  const size_t wbf = (size_t)nt * 65536 + (size_t)lane * 8;

  f32x16 hh, cr;
#pragma unroll
  for (int g = 0; g < 16; ++g) { hh[g] = 0.0f; cr[g] = 0.0f; }

  // ---- prologue: stage round 0 into buffer 0 ----
  if (stg) {
    const float4 a0 = *(const float4*)(xg + 0);
    const float4 a1 = *(const float4*)(xg + 4);
    half8 h, l;
    cvt8(a0, a1, h, l);
    *(half8*)(sm + wbase + wslot)        = h;
    *(half8*)(sm + wbase + 1024 + wslot) = l;
  }

  for (int r = 0; r < NRND; ++r) {
    __syncthreads();                       // buf (r&1) visible; (r&1)^1 free
    float4 p0, p1;
    if (stg && r + 1 < NRND) {             // issue next-round x loads early
      const float* xn = xg + (r + 1) * KRND;
      p0 = *(const float4*)(xn + 0);
      p1 = *(const float4*)(xn + 4);
    }
    const char* bb = sm + (r & 1) * 16384;
#pragma unroll
    for (int i = 0; i < 2; ++i) {
      const int s  = kw * 2 + i;
      const int fb = s * 2048;
      const int ai = ((lane ^ s ^ ((lane >> 5) << 2)) << 4);
      const half8 ah = *(const half8*)(bb + fb + ai);
      const half8 al = *(const half8*)(bb + fb + 1024 + ai);
      const size_t wo = wbf + (size_t)(r * 8 + s) * 512;
      const half8 bh = *(const half8*)(wsh + wo);
      const half8 bl = *(const half8*)(wsl + wo);
      hh = MFMA32(ah, bh, hh, 0, 0, 0);
      cr = MFMA32(ah, bl, cr, 0, 0, 0);
      cr = MFMA32(al, bh, cr, 0, 0, 0);
    }
    if (stg && r + 1 < NRND) {             // convert + write into free buffer
      half8 h, l;
      cvt8(p0, p1, h, l);
      char* dst = sm + ((r + 1) & 1) * 16384;
      *(half8*)(dst + wbase + wslot)        = h;
      *(half8*)(dst + wbase + 1024 + wslot) = l;
    }
  }
  __syncthreads();                         // GEMM staging LDS dead

  // ---- 4-way K-split reduce + unscale + rnn into A ----
  // 32x32 C/D layout: col = lane&31, row = (g&3) + 8*(g>>2) + 4*(lane>>5)
  {
    const int e = nt * 32 + (lane & 31);
    float v[16];
#pragma unroll
    for (int g = 0; g < 16; ++g)
      v[g] = hh[g] * (1.0f / 32.0f) + cr[g] * (1.0f / 65536.0f);
    if (kw == 1) {
#pragma unroll
      for (int g = 0; g < 16; ++g)
        S1[swz((g & 3) + 8 * (g >> 2) + 4 * (lane >> 5), e)] = v[g];
    } else if (kw == 2) {
#pragma unroll
      for (int g = 0; g < 16; ++g)
        S2[swz((g & 3) + 8 * (g >> 2) + 4 * (lane >> 5), e)] = v[g];
    } else if (kw == 3) {
#pragma unroll
      for (int g = 0; g < 16; ++g)
        S3[swz((g & 3) + 8 * (g >> 2) + 4 * (lane >> 5), e)] = v[g];
    }
    __syncthreads();
    if (kw == 0) {
      const float rv = rnn[e];
#pragma unroll
      for (int g = 0; g < 16; ++g) {
        const int idx = swz((g & 3) + 8 * (g >> 2) + 4 * (lane >> 5), e);
        A[idx] = v[g] + S1[idx] + S2[idx] + S3[idx] + rv;
      }
    }
  }
  __syncthreads();

  // ---- LayerNorm + exact GELU: 2 tokens per wave; G -> G4 (float4-swizzled) ----
  {
    const float gm0 = gamma[lane], gm1 = gamma[lane + 64];
    const float bt0 = beta[lane],  bt1 = beta[lane + 64];
    for (int tt = wv * 2; tt < wv * 2 + 2; ++tt) {
      const float v0 = A[swz(tt, lane)];
      const float v1 = A[swz(tt, lane + 64)];
      float s = v0 + v1;
#pragma unroll
      for (int m = 32; m; m >>= 1) s += __shfl_xor(s, m);
      const float mu = s * (1.0f / 128.0f);
      const float d0 = v0 - mu, d1 = v1 - mu;
      float q = d0 * d0 + d1 * d1;
#pragma unroll
      for (int m = 32; m; m >>= 1) q += __shfl_xor(q, m);
      const float rstd = 1.0f / sqrtf(q * (1.0f / 128.0f) + 1e-5f);
      const float h0v = d0 * rstd * gm0 + bt0;
      const float h1v = d1 * rstd * gm1 + bt1;
      const float g0 = 0.5f * h0v * (1.0f + erff(h0v * 0.70710678118654752f));
      const float g1 = 0.5f * h1v * (1.0f + erff(h1v * 0.70710678118654752f));
      const int e0a = lane, e1a = lane + 64;
      G4[(tt * 32 + (((e0a >> 2) ^ tt))) * 4 + (e0a & 3)] = g0;
      G4[(tt * 32 + (((e1a >> 2) ^ tt))) * 4 + (e1a & 3)] = g1;
    }
  }
  __syncthreads();

  // ---- decoder GEMM: wave = 8 h-rows x 32 tokens; lane halves split rows ----
  {
    float acc2[4] = {0.0f, 0.0f, 0.0f, 0.0f};
    const int tokn  = lane & 31;
    const int rbase = wv * 8 + (lane >> 5) * 4;
    const float4* wd4 = (const float4*)(Wd + (size_t)rbase * EDIM);
#pragma unroll 2
    for (int kg = 0; kg < EDIM / 4; ++kg) {
      const float4 gv = *(const float4*)&G4[(tokn * 32 + (kg ^ tokn)) * 4];
#pragma unroll
      for (int j = 0; j < 4; ++j) {
        const float4 w = wd4[(size_t)j * (EDIM / 4) + kg];
        acc2[j] = fmaf(gv.x, w.x,
                  fmaf(gv.y, w.y,
                  fmaf(gv.z, w.z,
                  fmaf(gv.w, w.w, acc2[j]))));
      }
    }
    __syncthreads();                 // all G4/A reads done block-wide
#pragma unroll
    for (int j = 0; j < 4; ++j) A[swz(tokn, rbase + j)] = acc2[j];
  }
  __syncthreads();

  // ---- gumbel-sigmoid, exact top-k (value then lower-index), output ----
  for (int tt = wv * 2; tt < wv * 2 + 2; ++tt) {
    const size_t T = (size_t)(t0 + tt);
    const float l0 = A[swz(tt, lane)];
    const float l1 = A[swz(tt, lane + 64)];
    const float gn0 = gum[T * HDIM + lane];
    const float gn1 = gum[T * HDIM + lane + 64];
    const float z0 = (l0 + gn0 + 3.0f) * 2.5f;
    const float z1 = (l1 + gn1 + 3.0f) * 2.5f;
    const float ba0 = 1.0f / (1.0f + expf(-z0));
    const float ba1 = 1.0f / (1.0f + expf(-z1));
    const unsigned ub0 = __float_as_uint(ba0);   // ba in (0,1]: bits monotone
    const unsigned ub1 = __float_as_uint(ba1);
    const int r0 = ba0 > 0.5f;                   // round: 0.5 -> 0
    const int r1 = ba1 > 0.5f;
    const int cnt = __popcll(__ballot(r0)) + __popcll(__ballot(r1));
    float bin0, bin1;
    if (cnt > 32) {
      // cnt>32 => 32nd-largest ba > 0.5 => its bits in (0x3F000000, 0x3F800000]
      // so fix the prefix and radix-select over the low 24 bits only.
      unsigned v = 0x3F000000u;
#pragma unroll
      for (int b = 23; b >= 0; --b) {
        const unsigned cand = v | (1u << b);
        const int cc = __popcll(__ballot(ub0 >= cand)) + __popcll(__ballot(ub1 >= cand));
        if (cc >= 32) v = cand;
      }
      const int cgt = __popcll(__ballot(ub0 > v)) + __popcll(__ballot(ub1 > v));
      const int r = 32 - cgt;                     // tied slots; lower index wins
      const unsigned long long t0b = __ballot(ub0 == v);
      const unsigned long long t1b = __ballot(ub1 == v);
      const int n0 = __popcll(t0b);
      const unsigned long long mlt = (1ull << lane) - 1ull;
      const int rk0 = __popcll(t0b & mlt);
      const int rk1 = n0 + __popcll(t1b & mlt);
      bin0 = (ub0 > v || (ub0 == v && rk0 < r)) ? 1.0f : 0.0f;
      bin1 = (ub1 > v || (ub1 == v && rk1 < r)) ? 1.0f : 0.0f;
    } else if (cnt == 0) {
      float m = fmaxf(ba0, ba1);
#pragma unroll
      for (int mm = 32; mm; mm >>= 1) m = fmaxf(m, __shfl_xor(m, mm));
      const unsigned long long e0b = __ballot(ba0 == m);
      const unsigned long long e1b = __ballot(ba1 == m);
      const int hstar = e0b ? (__ffsll((unsigned long long)e0b) - 1)
                            : (64 + __ffsll((unsigned long long)e1b) - 1);
      bin0 = (lane == hstar) ? 1.0f : 0.0f;
      bin1 = (lane + 64 == hstar) ? 1.0f : 0.0f;
    } else {
      bin0 = r0 ? 1.0f : 0.0f;
      bin1 = r1 ? 1.0f : 0.0f;
    }
    outb[T * HDIM + lane]      = bin0;
    outb[T * HDIM + lane + 64] = bin1;
    outa[T * HDIM + lane]      = ba0;
    outa[T * HDIM + lane + 64] = ba1;
  }
}

extern "C" void kernel_launch(void* const* d_in, const int* in_sizes, int n_in,
                              void* d_out, int out_size, void* d_ws, size_t ws_size,
                              hipStream_t stream) {
  (void)in_sizes; (void)n_in; (void)ws_size; (void)out_size;
  const float* x   = (const float*)d_in[0];
  const float* Wr  = (const float*)d_in[1];
  const float* Wd  = (const float*)d_in[2];
  const float* gm  = (const float*)d_in[3];
  const float* bt  = (const float*)d_in[4];
  const float* rnn = (const float*)d_in[5];
  const float* gum = (const float*)d_in[6];
  float* outb = (float*)d_out;
  float* outa = outb + (size_t)NTOK * HDIM;   // tuple: (binary, binary_approx)

  _Float16* wh = (_Float16*)d_ws;             // 512 KB
  _Float16* wl = wh + (size_t)EDIM * DDIM;    // 512 KB

  conv_w<<<dim3(128), dim3(256), 0, stream>>>(Wr, wh, wl);
  fused_router<<<dim3(NTOK / TOKT), dim3(1024), 0, stream>>>(
      x, wh, wl, Wd, gm, bt, rnn, gum, outb, outa);
}

// Round 9
// 249.341 us; speedup vs baseline: 1.0603x; 1.0603x over previous
//
#include <hip/hip_runtime.h>
#include <math.h>

#define NTOK   16384
#define DDIM   2048
#define EDIM   128
#define HDIM   128
#define TOKT   64
#define NRND   16            // rounds of 128 k each
#define KRND   128

typedef __attribute__((ext_vector_type(8)))  _Float16 half8;
typedef __attribute__((ext_vector_type(16))) float    f32x16;

#define MFMA32 __builtin_amdgcn_mfma_f32_32x32x16_f16

// b32-granule XOR swizzle for epilogue A[64][128]: conflict-free row+column.
__device__ __forceinline__ int swz(int t, int e) {
  return t * EDIM + ((e & 96) | ((e ^ t) & 31));
}

__device__ __forceinline__ void cvt8(const float4& a, const float4& b,
                                     half8& h, half8& l) {
#pragma unroll
  for (int m = 0; m < 4; ++m) {
    const float v = (&a.x)[m];
    const _Float16 hv = (_Float16)v;
    h[m] = hv; l[m] = (_Float16)((v - (float)hv) * 2048.0f);
  }
#pragma unroll
  for (int m = 0; m < 4; ++m) {
    const float v = (&b.x)[m];
    const _Float16 hv = (_Float16)v;
    h[m + 4] = hv; l[m + 4] = (_Float16)((v - (float)hv) * 2048.0f);
  }
}

// ---- W pre-convert: 32x32x16-fragment-ordered f16 hi/lo planes ----
// elem idx -> (nt, ks, lane, j); lane holds B[k=ks*16+(lane>>5)*8+j][n=nt*32+(lane&31)]
// = Wr[n][k], scaled by 32 (hi) and 32*2048 (lo) to dodge f16 denormals.
__global__ __launch_bounds__(256)
void conv_w(const float* __restrict__ Wr,
            _Float16* __restrict__ wh, _Float16* __restrict__ wl) {
  const int idx  = (int)blockIdx.x * 256 + (int)threadIdx.x;  // 0..32767
  const int lane = idx & 63;
  const int ks   = (idx >> 6) & 127;
  const int nt   = idx >> 13;                                 // 0..3
  const int n    = nt * 32 + (lane & 31);
  const int k0   = ks * 16 + (lane >> 5) * 8;
  half8 h, l;
#pragma unroll
  for (int j = 0; j < 8; ++j) {
    const float w = Wr[(size_t)n * DDIM + k0 + j] * 32.0f;
    const _Float16 hh = (_Float16)w;
    h[j] = hh;
    l[j] = (_Float16)((w - (float)hh) * 2048.0f);
  }
  *(half8*)(wh + (size_t)idx * 8) = h;
  *(half8*)(wl + (size_t)idx * 8) = l;
}

__global__ __launch_bounds__(1024, 4)
void fused_router(const float* __restrict__ x,
                  const _Float16* __restrict__ wsh,
                  const _Float16* __restrict__ wsl,
                  const float* __restrict__ Wd,
                  const float* __restrict__ gamma,
                  const float* __restrict__ beta,
                  const float* __restrict__ rnn,
                  const float* __restrict__ gum,
                  float* __restrict__ outb,
                  float* __restrict__ outa) {
  // Producer/consumer decoupled GEMM: NO block barrier in the main loop.
  //   Ring: 4 slots x 32 KB (64 tok x 128 k, f16 hi/lo, r5's verified
  //   fragment swizzle). Waves 8..15 = producers (group 0: even rounds,
  //   group 1: odd rounds; 2-round register lookahead; gated only by ring
  //   slot availability). Waves 0..7 = consumers (one 32x32 C tile each,
  //   full K; gated per-slot by LDS flag counters).
  //   Flags: prod_cnt[16] (ready at 4 = waves/group), cons_cnt[16]
  //   (free at 8 = consumer waves). LANE 0 ONLY does the atomicAdd —
  //   per-lane atomics coalesce to +64/wave (m20) and broke r8's gates.
  // Epilogue overlays ring slots 0/1: A = [0,32K), G4 = [32K,64K).
  __shared__ char smraw[131200];
  char* const sm = smraw;
  float* const A  = (float*)smraw;
  float* const G4 = (float*)(smraw + 32768);
  int* const prod_cnt = (int*)(smraw + 131072);
  int* const cons_cnt = prod_cnt + 16;

  const int tid  = (int)threadIdx.x;
  const int wv   = __builtin_amdgcn_readfirstlane(tid >> 6);  // 0..15
  const int lane = tid & 63;
  const int t0   = (int)blockIdx.x * TOKT;

  if (tid < 32) prod_cnt[tid] = 0;       // zero both flag arrays
  __syncthreads();

  if (wv < 8) {
    // ================= CONSUMER: one 32x32 tile, full K =================
    const int mw = wv >> 2;              // token half
    const int nt = wv & 3;               // e quarter
    const size_t wbf = (size_t)nt * 65536 + (size_t)lane * 8;

    f32x16 hh, cr;
#pragma unroll
    for (int g = 0; g < 16; ++g) { hh[g] = 0.0f; cr[g] = 0.0f; }

    for (int r = 0; r < NRND; ++r) {
      {                                  // wait: slot r%4 filled for round r
        volatile int* pf = &prod_cnt[r];
        while (*pf < 4) __builtin_amdgcn_s_sleep(1);
      }
      asm volatile("" ::: "memory");     // no hoisting of reads above spin
      __builtin_amdgcn_sched_barrier(0);
      const char* bb = sm + (r & 3) * 32768;
#pragma unroll
      for (int s = 0; s < 8; ++s) {
        const int fb = (s * 2 + mw) * 2048;
        const int ai = ((lane ^ s ^ ((lane >> 5) << 2)) << 4);
        const half8 ah = *(const half8*)(bb + fb + ai);
        const half8 al = *(const half8*)(bb + fb + 1024 + ai);
        const size_t wo = wbf + (size_t)(r * 8 + s) * 512;
        const half8 bh = *(const half8*)(wsh + wo);
        const half8 bl = *(const half8*)(wsl + wo);
        hh = MFMA32(ah, bh, hh, 0, 0, 0);
        cr = MFMA32(ah, bl, cr, 0, 0, 0);
        cr = MFMA32(al, bh, cr, 0, 0, 0);
      }
      __threadfence_block();             // slot reads retired before release
      if (lane == 0) atomicAdd(&cons_cnt[r], 1);   // exact wave count
    }
    __syncthreads();                     // ring dead; A/G4 overlay safe

    // ---- unscale + rnn into A (C/D: col=lane&31, row=(g&3)+8*(g>>2)+4*(lane>>5)) ----
    {
      const int e = nt * 32 + (lane & 31);
      const float rv = rnn[e];
#pragma unroll
      for (int g = 0; g < 16; ++g) {
        const int row = (g & 3) + 8 * (g >> 2) + 4 * (lane >> 5);
        A[swz(mw * 32 + row, e)] =
            hh[g] * (1.0f / 32.0f) + cr[g] * (1.0f / 65536.0f) + rv;
      }
    }
  } else {
    // ================= PRODUCER: stream x through the ring =================
    const int pw = wv - 8;               // 0..7
    const int g  = pw >> 2;              // group: 0 = even rounds, 1 = odd
    const int gt = (pw & 3) * 64 + lane; // 0..255 within group
    const int t  = gt >> 2;              // token 0..63
    const int kb = gt & 3;               // 32-k block within round
    const float* xg = x + (size_t)(t0 + t) * DDIM + kb * 32;
    const int mtb  = (t >> 5);           // token half (LDS region select)

    float4 qa[8], qb[8];
    auto pload = [&](int rr, float4* q) {
#pragma unroll
      for (int p = 0; p < 8; ++p)
        q[p] = *(const float4*)(xg + (size_t)rr * KRND + p * 4);
    };
    auto pwrite = [&](int rr, const float4* q) {
      if (rr >= 4) {                     // wait: slot rr%4 free (round rr-4 consumed)
        volatile int* cf = &cons_cnt[rr - 4];
        while (*cf < 8) __builtin_amdgcn_s_sleep(1);
      }
      asm volatile("" ::: "memory");     // no sinking of writes above spin
      __builtin_amdgcn_sched_barrier(0);
      char* sb = sm + (rr & 3) * 32768;
#pragma unroll
      for (int p = 0; p < 4; ++p) {
        const int s  = kb * 2 + (p >> 1);
        const int ko = p & 1;
        half8 h, l;
        cvt8(q[2 * p], q[2 * p + 1], h, l);
        const int base = (s * 2 + mtb) * 2048;
        const int slot = ((ko * 32 + (t & 31)) ^ s ^ (ko * 4)) * 16;
        *(half8*)(sb + base + slot)        = h;
        *(half8*)(sb + base + 1024 + slot) = l;
      }
      __threadfence_block();             // writes visible before flag
      if (lane == 0) atomicAdd(&prod_cnt[rr], 1);  // exact wave count
    };

    pload(g, qa);                        // 2-round lookahead in registers
    pload(g + 2, qb);
#pragma unroll
    for (int i = 0; i < 8; i += 2) {
      pwrite(g + 2 * i, qa);
      if (i + 2 < 8) pload(g + 2 * (i + 2), qa);
      pwrite(g + 2 * (i + 1), qb);
      if (i + 3 < 8) pload(g + 2 * (i + 3), qb);
    }
    __syncthreads();                     // matches consumer-side barrier
  }
  __syncthreads();                       // A complete for all waves

  // ---- LayerNorm + exact GELU: 4 tokens per wave; G -> G4 (float4-swizzled) ----
  const int e0 = wv * 8;                 // decoder e-mapping
  {
    const float gm0 = gamma[lane], gm1 = gamma[lane + 64];
    const float bt0 = beta[lane],  bt1 = beta[lane + 64];
    for (int tt = wv * 4; tt < wv * 4 + 4; ++tt) {
      const float v0 = A[swz(tt, lane)];
      const float v1 = A[swz(tt, lane + 64)];
      float s = v0 + v1;
#pragma unroll
      for (int m = 32; m; m >>= 1) s += __shfl_xor(s, m);
      const float mu = s * (1.0f / 128.0f);
      const float d0 = v0 - mu, d1 = v1 - mu;
      float q = d0 * d0 + d1 * d1;
#pragma unroll
      for (int m = 32; m; m >>= 1) q += __shfl_xor(q, m);
      const float rstd = 1.0f / sqrtf(q * (1.0f / 128.0f) + 1e-5f);
      const float h0v = d0 * rstd * gm0 + bt0;
      const float h1v = d1 * rstd * gm1 + bt1;
      const float g0 = 0.5f * h0v * (1.0f + erff(h0v * 0.70710678118654752f));
      const float g1 = 0.5f * h1v * (1.0f + erff(h1v * 0.70710678118654752f));
      const int e0a = lane, e1a = lane + 64;
      G4[(tt * 32 + (((e0a >> 2) ^ (tt & 31)))) * 4 + (e0a & 3)] = g0;
      G4[(tt * 32 + (((e1a >> 2) ^ (tt & 31)))) * 4 + (e1a & 3)] = g1;
    }
  }
  __syncthreads();

  // ---- decoder GEMM: wave = 8 h-rows x 64 tokens (lane = token) ----
  {
    float acc2[8];
#pragma unroll
    for (int j = 0; j < 8; ++j) acc2[j] = 0.0f;
    const float4* wd4 = (const float4*)(Wd + (size_t)e0 * EDIM);  // uniform
#pragma unroll 2
    for (int kg = 0; kg < EDIM / 4; ++kg) {
      const float4 gv = *(const float4*)&G4[(lane * 32 + (kg ^ (lane & 31))) * 4];
#pragma unroll
      for (int j = 0; j < 8; ++j) {
        const float4 w = wd4[(size_t)j * (EDIM / 4) + kg];
        acc2[j] = fmaf(gv.x, w.x,
                  fmaf(gv.y, w.y,
                  fmaf(gv.z, w.z,
                  fmaf(gv.w, w.w, acc2[j]))));
      }
    }
    __syncthreads();                 // all G4 reads done block-wide
#pragma unroll
    for (int j = 0; j < 8; ++j) A[swz(lane, e0 + j)] = acc2[j];
  }
  __syncthreads();

  // ---- gumbel-sigmoid, exact top-k (value then lower-index), output ----
  for (int tt = wv * 4; tt < wv * 4 + 4; ++tt) {
    const size_t T = (size_t)(t0 + tt);
    const float l0 = A[swz(tt, lane)];
    const float l1 = A[swz(tt, lane + 64)];
    const float gn0 = gum[T * HDIM + lane];
    const float gn1 = gum[T * HDIM + lane + 64];
    const float z0 = (l0 + gn0 + 3.0f) * 2.5f;
    const float z1 = (l1 + gn1 + 3.0f) * 2.5f;
    const float ba0 = 1.0f / (1.0f + expf(-z0));
    const float ba1 = 1.0f / (1.0f + expf(-z1));
    const unsigned ub0 = __float_as_uint(ba0);   // ba in (0,1]: bits monotone
    const unsigned ub1 = __float_as_uint(ba1);
    const int r0 = ba0 > 0.5f;                   // round: 0.5 -> 0
    const int r1 = ba1 > 0.5f;
    const int cnt = __popcll(__ballot(r0)) + __popcll(__ballot(r1));
    float bin0, bin1;
    if (cnt > 32) {
      // cnt>32 => 32nd-largest ba > 0.5 => its bits in (0x3F000000, 0x3F800000]
      // so fix the prefix and radix-select over the low 24 bits only.
      unsigned v = 0x3F000000u;
#pragma unroll
      for (int b = 23; b >= 0; --b) {
        const unsigned cand = v | (1u << b);
        const int cc = __popcll(__ballot(ub0 >= cand)) + __popcll(__ballot(ub1 >= cand));
        if (cc >= 32) v = cand;
      }
      const int cgt = __popcll(__ballot(ub0 > v)) + __popcll(__ballot(ub1 > v));
      const int r = 32 - cgt;                     // tied slots; lower index wins
      const unsigned long long t0b = __ballot(ub0 == v);
      const unsigned long long t1b = __ballot(ub1 == v);
      const int n0 = __popcll(t0b);
      const unsigned long long mlt = (1ull << lane) - 1ull;
      const int rk0 = __popcll(t0b & mlt);
      const int rk1 = n0 + __popcll(t1b & mlt);
      bin0 = (ub0 > v || (ub0 == v && rk0 < r)) ? 1.0f : 0.0f;
      bin1 = (ub1 > v || (ub1 == v && rk1 < r)) ? 1.0f : 0.0f;
    } else if (cnt == 0) {
      float m = fmaxf(ba0, ba1);
#pragma unroll
      for (int mm = 32; mm; mm >>= 1) m = fmaxf(m, __shfl_xor(m, mm));
      const unsigned long long e0b = __ballot(ba0 == m);
      const unsigned long long e1b = __ballot(ba1 == m);
      const int hstar = e0b ? (__ffsll((unsigned long long)e0b) - 1)
                            : (64 + __ffsll((unsigned long long)e1b) - 1);
      bin0 = (lane == hstar) ? 1.0f : 0.0f;
      bin1 = (lane + 64 == hstar) ? 1.0f : 0.0f;
    } else {
      bin0 = r0 ? 1.0f : 0.0f;
      bin1 = r1 ? 1.0f : 0.0f;
    }
    outb[T * HDIM + lane]      = bin0;
    outb[T * HDIM + lane + 64] = bin1;
    outa[T * HDIM + lane]      = ba0;
    outa[T * HDIM + lane + 64] = ba1;
  }
}

extern "C" void kernel_launch(void* const* d_in, const int* in_sizes, int n_in,
                              void* d_out, int out_size, void* d_ws, size_t ws_size,
                              hipStream_t stream) {
  (void)in_sizes; (void)n_in; (void)ws_size; (void)out_size;
  const float* x   = (const float*)d_in[0];
  const float* Wr  = (const float*)d_in[1];
  const float* Wd  = (const float*)d_in[2];
  const float* gm  = (const float*)d_in[3];
  const float* bt  = (const float*)d_in[4];
  const float* rnn = (const float*)d_in[5];
  const float* gum = (const float*)d_in[6];
  float* outb = (float*)d_out;
  float* outa = outb + (size_t)NTOK * HDIM;   // tuple: (binary, binary_approx)

  _Float16* wh = (_Float16*)d_ws;             // 512 KB
  _Float16* wl = wh + (size_t)EDIM * DDIM;    // 512 KB

  conv_w<<<dim3(128), dim3(256), 0, stream>>>(Wr, wh, wl);
  fused_router<<<dim3(NTOK / TOKT), dim3(1024), 0, stream>>>(
      x, wh, wl, Wd, gm, bt, rnn, gum, outb, outa);
}